// Round 6
// baseline (179.055 us; speedup 1.0000x reference)
//
#include <hip/hip_runtime.h>
#include <hip/hip_bf16.h>

#define NN 10000
#define NE 640000
#define D_IN 128
#define D_H 128
#define N_CLS 64
#define CAP 160    // per-node capacity: deg ~ Binom(640K,1e-4) mean 64 sigma 8 -> +12 sigma
#define GRP 157    // coarse groups: dst>>6 (64 nodes/group)
#define CAPC 4800  // per-group coarse capacity: mean 4096 sigma 64 -> +11 sigma
#define EPB 4096   // edges per phase-A block
#define AB 157     // phase-A edge blocks (157*4096 >= 640000)
#define CB 1250    // conv blocks: NN*D_IN/4/256

// ---- bf16 helpers ----
__device__ __forceinline__ float blo(unsigned u) { return __uint_as_float(u << 16); }
__device__ __forceinline__ float bhi(unsigned u) { return __uint_as_float(u & 0xffff0000u); }
__device__ __forceinline__ unsigned short f2bf(float f) {
    unsigned u = __float_as_uint(f);
    return (unsigned short)((u + 0x7fffu + ((u >> 16) & 1u)) >> 16);
}

// ---- Phase A: coarse-bucket edges (dst>>6) + fused f32->bf16 feature conv ----
__global__ __launch_bounds__(256) void prep_a(const int* __restrict__ src,
                                              const int* __restrict__ dst,
                                              int* __restrict__ coarse_cnt,
                                              unsigned* __restrict__ coarse,
                                              const float* __restrict__ feat,
                                              unsigned* __restrict__ hb0) {
    int bid = blockIdx.x;
    if (bid >= AB) {   // ---- conv part ----
        int t = (bid - AB) * 256 + threadIdx.x;
        if (t < NN * D_IN / 4) {
            float4 f = ((const float4*)feat)[t];
            unsigned lo = (unsigned)f2bf(f.x) | ((unsigned)f2bf(f.y) << 16);
            unsigned hi = (unsigned)f2bf(f.z) | ((unsigned)f2bf(f.w) << 16);
            ((uint2*)hb0)[t] = make_uint2(lo, hi);
        }
        return;
    }
    __shared__ unsigned stage[EPB];
    __shared__ int hist[GRP], gbase[GRP], cur[GRP];
    const int t = threadIdx.x;
    for (int i = t; i < GRP; i += 256) hist[i] = 0;
    __syncthreads();
    const int e0 = bid * EPB;
    const int ecnt = min(EPB, NE - e0);
    for (int i = t; i < ecnt; i += 256) {
        int s = src[e0 + i];
        int d = dst[e0 + i];
        stage[i] = (unsigned)s | ((unsigned)d << 16);
        atomicAdd(&hist[d >> 6], 1);
    }
    __syncthreads();
    for (int i = t; i < GRP; i += 256) {
        gbase[i] = atomicAdd(&coarse_cnt[i], hist[i]);
        cur[i] = 0;
    }
    __syncthreads();
    for (int i = t; i < ecnt; i += 256) {
        unsigned u = stage[i];
        int g = u >> 22;                 // dst >> 6
        int r = atomicAdd(&cur[g], 1);
        coarse[g * CAPC + gbase[g] + r] = u;
    }
}

// ---- Phase B: per-group scatter into per-node colbuf (single-block regions) ----
__global__ __launch_bounds__(256) void prep_b(const int* __restrict__ coarse_cnt,
                                              const unsigned* __restrict__ coarse,
                                              int* __restrict__ cnt,
                                              int* __restrict__ colbuf) {
    __shared__ int cur[64];
    const int g = blockIdx.x;
    const int t = threadIdx.x;
    if (t < 64) cur[t] = 0;
    __syncthreads();
    const int m = coarse_cnt[g];
    const unsigned* cb = coarse + g * CAPC;
    for (int i = t; i < m; i += 256) {
        unsigned u = cb[i];
        int s = (int)(u & 0xFFFFu);
        int d = (int)(u >> 16);
        int r = atomicAdd(&cur[d - (g << 6)], 1);
        colbuf[d * CAP + r] = s;
    }
    __syncthreads();
    int n = (g << 6) + t;
    if (t < 64 && n < NN) cnt[n] = cur[t];
}

// ---- fused layer: M nodes/block; deep-ILP gather + (h+agg)@W ----
// Block = 256 threads = 4 waves; wave handles M/4 nodes sequentially.
// Gather: 16 lanes per 256B bf16 row (uint4/lane); full 64-neighbor batches are
// fully unrolled -> 16 independent uint4 loads in flight per wave.
template <int J, int M, bool LAST>
__global__ __launch_bounds__(256) void gin_layer(const uint4* __restrict__ hb4,   // N x 16 uint4
                                                 const int* __restrict__ cnt,
                                                 const int* __restrict__ colbuf,
                                                 const float* __restrict__ W,     // 128 x J
                                                 unsigned short* __restrict__ outb,
                                                 float* __restrict__ outf) {
    __shared__ float xs[M][D_H];
    const int base = blockIdx.x * M;
    const int tid = threadIdx.x;
    const int wave = tid >> 6;
    const int lane = tid & 63;
    const int sub = lane >> 4;    // which of 4 rows in a load-group
    const int off = lane & 15;    // uint4 offset within a row

#pragma unroll 1
    for (int nm = 0; nm < M / 4; ++nm) {
        const int m = wave + nm * 4;
        const int n = base + m;
        float a0, a1, a2, a3, a4, a5, a6, a7;
        if (sub == 0) {           // own row (eps=0: h + agg), counted once
            uint4 u = hb4[n * 16 + off];
            a0 = blo(u.x); a1 = bhi(u.x); a2 = blo(u.y); a3 = bhi(u.y);
            a4 = blo(u.z); a5 = bhi(u.z); a6 = blo(u.w); a7 = bhi(u.w);
        } else {
            a0 = a1 = a2 = a3 = a4 = a5 = a6 = a7 = 0.f;
        }
        const int d = cnt[n];
        const int* cl = colbuf + n * CAP;
        int b = 0;
        // full 64-neighbor batches: 16 loads in flight
        for (; b + 64 <= d; b += 64) {
            int c = __builtin_nontemporal_load(&cl[b + lane]);
            uint4 u[16];
#pragma unroll
            for (int q = 0; q < 16; ++q) {
                int s = __shfl(c, q * 4 + sub);
                u[q] = hb4[s * 16 + off];
            }
#pragma unroll
            for (int q = 0; q < 16; ++q) {
                a0 += blo(u[q].x); a1 += bhi(u[q].x);
                a2 += blo(u[q].y); a3 += bhi(u[q].y);
                a4 += blo(u[q].z); a5 += bhi(u[q].z);
                a6 += blo(u[q].w); a7 += bhi(u[q].w);
            }
        }
        // tail
        const int cb = d - b;
        if (cb > 0) {
            int c = (lane < cb) ? __builtin_nontemporal_load(&cl[b + lane]) : 0;
            int i = 0;
            for (; i + 4 <= cb; i += 4) {
                int s = __shfl(c, i + sub);
                uint4 u = hb4[s * 16 + off];
                a0 += blo(u.x); a1 += bhi(u.x); a2 += blo(u.y); a3 += bhi(u.y);
                a4 += blo(u.z); a5 += bhi(u.z); a6 += blo(u.w); a7 += bhi(u.w);
            }
            const int rem = cb - i;
            if (rem > 0) {
                int s = __shfl(c, i + (sub < rem ? sub : 0));
                uint4 u = make_uint4(0, 0, 0, 0);
                if (sub < rem) u = hb4[s * 16 + off];
                a0 += blo(u.x); a1 += bhi(u.x); a2 += blo(u.y); a3 += bhi(u.y);
                a4 += blo(u.z); a5 += bhi(u.z); a6 += blo(u.w); a7 += bhi(u.w);
            }
        }
        // reduce the 4 sub-rows
        a0 += __shfl_xor(a0, 16); a0 += __shfl_xor(a0, 32);
        a1 += __shfl_xor(a1, 16); a1 += __shfl_xor(a1, 32);
        a2 += __shfl_xor(a2, 16); a2 += __shfl_xor(a2, 32);
        a3 += __shfl_xor(a3, 16); a3 += __shfl_xor(a3, 32);
        a4 += __shfl_xor(a4, 16); a4 += __shfl_xor(a4, 32);
        a5 += __shfl_xor(a5, 16); a5 += __shfl_xor(a5, 32);
        a6 += __shfl_xor(a6, 16); a6 += __shfl_xor(a6, 32);
        a7 += __shfl_xor(a7, 16); a7 += __shfl_xor(a7, 32);
        if (sub == 0) {
            *(float4*)&xs[m][8 * off]     = make_float4(a0, a1, a2, a3);
            *(float4*)&xs[m][8 * off + 4] = make_float4(a4, a5, a6, a7);
        }
    }
    __syncthreads();

    // ---- GEMM phase ----
    constexpr int G = 256 / J;
    constexpr int NM = M / G;
    const int g = tid / J;
    const int j = tid % J;
    const int mbase = g * NM;
    float acc[NM];
#pragma unroll
    for (int m = 0; m < NM; ++m) acc[m] = 0.f;

    for (int k = 0; k < D_H; k += 4) {
        float w0 = W[(k + 0) * J + j];
        float w1 = W[(k + 1) * J + j];
        float w2 = W[(k + 2) * J + j];
        float w3 = W[(k + 3) * J + j];
#pragma unroll
        for (int m = 0; m < NM; ++m) {
            float4 xv = *(const float4*)&xs[mbase + m][k];   // wave-uniform broadcast
            acc[m] += xv.x * w0 + xv.y * w1 + xv.z * w2 + xv.w * w3;
        }
    }
#pragma unroll
    for (int m = 0; m < NM; ++m) {
        int n = base + mbase + m;
        if (LAST) __builtin_nontemporal_store(acc[m], &outf[(size_t)n * J + j]);
        else      __builtin_nontemporal_store(f2bf(acc[m]), &outb[(size_t)n * J + j]);
    }
}

extern "C" void kernel_launch(void* const* d_in, const int* in_sizes, int n_in,
                              void* d_out, int out_size, void* d_ws, size_t ws_size,
                              hipStream_t stream) {
    const float* features = (const float*)d_in[0];
    const float* W0       = (const float*)d_in[1];
    const float* W1       = (const float*)d_in[2];
    const float* W2       = (const float*)d_in[3];
    const int*   src      = (const int*)d_in[4];
    const int*   dst      = (const int*)d_in[5];
    float* out = (float*)d_out;

    // Workspace: coarse_cnt | cnt | colbuf | coarse | hb0 | hb1 | hb2 (~17 MB)
    int* coarse_cnt = (int*)d_ws;                        // 160 ints
    int* cnt        = coarse_cnt + 160;                  // NN
    int* colbuf     = cnt + NN;                          // NN*CAP
    unsigned* coarse = (unsigned*)(colbuf + NN * CAP);   // GRP*CAPC
    unsigned* hb0   = coarse + (size_t)GRP * CAPC;       // N*64 uints
    unsigned* hb1   = hb0 + NN * 64;
    unsigned* hb2   = hb1 + NN * 64;

    hipMemsetAsync(coarse_cnt, 0, GRP * sizeof(int), stream);
    prep_a<<<AB + CB, 256, 0, stream>>>(src, dst, coarse_cnt, coarse, features, hb0);
    prep_b<<<GRP, 256, 0, stream>>>(coarse_cnt, coarse, cnt, colbuf);

    constexpr int M = 8;           // 10000/8 = 1250 blocks -> ~4.9 waves/SIMD
    gin_layer<D_H, M, false><<<NN / M, 256, 0, stream>>>((const uint4*)hb0, cnt, colbuf, W0,
                                                         (unsigned short*)hb1, nullptr);
    gin_layer<D_H, M, false><<<NN / M, 256, 0, stream>>>((const uint4*)hb1, cnt, colbuf, W1,
                                                         (unsigned short*)hb2, nullptr);
    gin_layer<N_CLS, M, true><<<NN / M, 256, 0, stream>>>((const uint4*)hb2, cnt, colbuf, W2,
                                                          nullptr, out);
}

// Round 7
// 149.349 us; speedup vs baseline: 1.1989x; 1.1989x over previous
//
#include <hip/hip_runtime.h>
#include <hip/hip_bf16.h>

#define NN 10000
#define NE 640000
#define D_IN 128
#define D_H 128
#define N_CLS 64
#define CAP 160    // per-node capacity (ushort entries): mean 64 sigma 8 -> +12 sigma
#define GRP 157    // coarse groups: dst>>6 (64 nodes/group)
#define CAPC 4800  // per-group coarse capacity: mean 4096 sigma 64 -> +11 sigma
#define EPB 4096   // edges per phase-A block
#define AB 157     // phase-A edge blocks (157*4096 >= 640000)
#define CB 1251    // conv blocks: (NN+1)*D_IN/4/256 rounded up (includes zero row NN)

// ---- bf16 helpers ----
__device__ __forceinline__ float blo(unsigned u) { return __uint_as_float(u << 16); }
__device__ __forceinline__ float bhi(unsigned u) { return __uint_as_float(u & 0xffff0000u); }
__device__ __forceinline__ unsigned short f2bf(float f) {
    unsigned u = __float_as_uint(f);
    return (unsigned short)((u + 0x7fffu + ((u >> 16) & 1u)) >> 16);
}

// ---- Phase A: coarse-bucket edges (dst>>6) + fused f32->bf16 feature conv ----
__global__ __launch_bounds__(256) void prep_a(const int* __restrict__ src,
                                              const int* __restrict__ dst,
                                              int* __restrict__ coarse_cnt,
                                              unsigned* __restrict__ coarse,
                                              const float* __restrict__ feat,
                                              unsigned* __restrict__ hb0) {
    int bid = blockIdx.x;
    if (bid >= AB) {   // ---- conv part: fill (NN+1) x 128 bf16 table (row NN = zeros) ----
        int t = (bid - AB) * 256 + threadIdx.x;   // uint2 units, 4 elems each
        if (t < NN * 32) {
            float4 f = ((const float4*)feat)[t];
            unsigned lo = (unsigned)f2bf(f.x) | ((unsigned)f2bf(f.y) << 16);
            unsigned hi = (unsigned)f2bf(f.z) | ((unsigned)f2bf(f.w) << 16);
            ((uint2*)hb0)[t] = make_uint2(lo, hi);
        } else if (t < (NN + 1) * 32) {
            ((uint2*)hb0)[t] = make_uint2(0u, 0u);   // sentinel zero row
        }
        return;
    }
    __shared__ unsigned stage[EPB];
    __shared__ int hist[GRP], gbase[GRP], cur[GRP];
    const int t = threadIdx.x;
    for (int i = t; i < GRP; i += 256) hist[i] = 0;
    __syncthreads();
    const int e0 = bid * EPB;
    const int ecnt = min(EPB, NE - e0);
    for (int i = t; i < ecnt; i += 256) {
        int s = src[e0 + i];
        int d = dst[e0 + i];
        stage[i] = (unsigned)s | ((unsigned)d << 16);
        atomicAdd(&hist[d >> 6], 1);
    }
    __syncthreads();
    for (int i = t; i < GRP; i += 256) {
        gbase[i] = atomicAdd(&coarse_cnt[i], hist[i]);
        cur[i] = 0;
    }
    __syncthreads();
    for (int i = t; i < ecnt; i += 256) {
        unsigned u = stage[i];
        int g = u >> 22;                 // dst >> 6
        int r = atomicAdd(&cur[g], 1);
        coarse[g * CAPC + gbase[g] + r] = u;
    }
}

// ---- Phase B: per-group scatter into per-node ushort colbuf + pad to x4 ----
__global__ __launch_bounds__(256) void prep_b(const int* __restrict__ coarse_cnt,
                                              const unsigned* __restrict__ coarse,
                                              int* __restrict__ cnt,
                                              unsigned short* __restrict__ colbuf) {
    __shared__ int cur[64];
    const int g = blockIdx.x;
    const int t = threadIdx.x;
    if (t < 64) cur[t] = 0;
    __syncthreads();
    const int m = coarse_cnt[g];
    const unsigned* cb = coarse + g * CAPC;
    for (int i = t; i < m; i += 256) {
        unsigned u = cb[i];
        int s = (int)(u & 0xFFFFu);
        int d = (int)(u >> 16);
        int r = atomicAdd(&cur[d - (g << 6)], 1);
        colbuf[d * CAP + r] = (unsigned short)s;
    }
    __syncthreads();
    if (t < 64) {
        int n = (g << 6) + t;
        if (n < NN) {
            int c = cur[t];
            int pad = (4 - (c & 3)) & 3;             // pad with sentinel NN (zero row)
            unsigned short* base = colbuf + n * CAP;
            for (int k = 0; k < pad; ++k) base[c + k] = (unsigned short)NN;
            cnt[n] = c + pad;
        }
    }
}

// ---- fused layer: M nodes/block; shfl-free tail-free gather + (h+agg)@W ----
// Block = 256 threads = 4 waves; wave handles M/4 nodes sequentially.
// 16 lanes per 256B bf16 row (uint4/lane); 4 rows per index-group; indices come
// from an 8B broadcast uint2 load (no shfl on the address path); lists are
// padded to x4 with sentinel NN -> no tail. Main loop unrolled x4 = 16 loads.
template <int J, int M, bool LAST>
__global__ __launch_bounds__(256) void gin_layer(const uint4* __restrict__ hb4,   // (NN+1) x 16 uint4
                                                 const int* __restrict__ cnt,
                                                 const unsigned short* __restrict__ colbuf,
                                                 const float* __restrict__ W,     // 128 x J
                                                 unsigned short* __restrict__ outb,
                                                 float* __restrict__ outf) {
    __shared__ float xs[M][D_H];
    const int base = blockIdx.x * M;
    const int tid = threadIdx.x;
    const int wave = tid >> 6;
    const int lane = tid & 63;
    const int sub = lane >> 4;    // which of 4 rows in an index-group
    const int off = lane & 15;    // uint4 offset within a row

#pragma unroll 1
    for (int nm = 0; nm < M / 4; ++nm) {
        const int m = wave + nm * 4;
        const int n = base + m;
        float a0, a1, a2, a3, a4, a5, a6, a7;
        if (sub == 0) {           // own row (eps=0: h + agg), counted once
            uint4 u = hb4[n * 16 + off];
            a0 = blo(u.x); a1 = bhi(u.x); a2 = blo(u.y); a3 = bhi(u.y);
            a4 = blo(u.z); a5 = bhi(u.z); a6 = blo(u.w); a7 = bhi(u.w);
        } else {
            a0 = a1 = a2 = a3 = a4 = a5 = a6 = a7 = 0.f;
        }
        const int G4 = cnt[n] >> 2;                 // index-groups of 4 rows
        const uint2* cl8 = (const uint2*)(colbuf + n * CAP);
        int g = 0;
        for (; g + 4 <= G4; g += 4) {               // 16 rows in flight
            uint2 p0 = cl8[g + 0];
            uint2 p1 = cl8[g + 1];
            uint2 p2 = cl8[g + 2];
            uint2 p3 = cl8[g + 3];
            unsigned w0 = (sub & 2) ? p0.y : p0.x;
            unsigned w1 = (sub & 2) ? p1.y : p1.x;
            unsigned w2 = (sub & 2) ? p2.y : p2.x;
            unsigned w3 = (sub & 2) ? p3.y : p3.x;
            int s0 = (sub & 1) ? (w0 >> 16) : (w0 & 0xffffu);
            int s1 = (sub & 1) ? (w1 >> 16) : (w1 & 0xffffu);
            int s2 = (sub & 1) ? (w2 >> 16) : (w2 & 0xffffu);
            int s3 = (sub & 1) ? (w3 >> 16) : (w3 & 0xffffu);
            uint4 uA = hb4[s0 * 16 + off];
            uint4 uB = hb4[s1 * 16 + off];
            uint4 uC = hb4[s2 * 16 + off];
            uint4 uD = hb4[s3 * 16 + off];
            a0 += (blo(uA.x) + blo(uB.x)) + (blo(uC.x) + blo(uD.x));
            a1 += (bhi(uA.x) + bhi(uB.x)) + (bhi(uC.x) + bhi(uD.x));
            a2 += (blo(uA.y) + blo(uB.y)) + (blo(uC.y) + blo(uD.y));
            a3 += (bhi(uA.y) + bhi(uB.y)) + (bhi(uC.y) + bhi(uD.y));
            a4 += (blo(uA.z) + blo(uB.z)) + (blo(uC.z) + blo(uD.z));
            a5 += (bhi(uA.z) + bhi(uB.z)) + (bhi(uC.z) + bhi(uD.z));
            a6 += (blo(uA.w) + blo(uB.w)) + (blo(uC.w) + blo(uD.w));
            a7 += (bhi(uA.w) + bhi(uB.w)) + (bhi(uC.w) + bhi(uD.w));
        }
        for (; g < G4; ++g) {                       // <=3 remainder groups
            uint2 p = cl8[g];
            unsigned w = (sub & 2) ? p.y : p.x;
            int s = (sub & 1) ? (w >> 16) : (w & 0xffffu);
            uint4 u = hb4[s * 16 + off];
            a0 += blo(u.x); a1 += bhi(u.x); a2 += blo(u.y); a3 += bhi(u.y);
            a4 += blo(u.z); a5 += bhi(u.z); a6 += blo(u.w); a7 += bhi(u.w);
        }
        // reduce the 4 sub-rows
        a0 += __shfl_xor(a0, 16); a0 += __shfl_xor(a0, 32);
        a1 += __shfl_xor(a1, 16); a1 += __shfl_xor(a1, 32);
        a2 += __shfl_xor(a2, 16); a2 += __shfl_xor(a2, 32);
        a3 += __shfl_xor(a3, 16); a3 += __shfl_xor(a3, 32);
        a4 += __shfl_xor(a4, 16); a4 += __shfl_xor(a4, 32);
        a5 += __shfl_xor(a5, 16); a5 += __shfl_xor(a5, 32);
        a6 += __shfl_xor(a6, 16); a6 += __shfl_xor(a6, 32);
        a7 += __shfl_xor(a7, 16); a7 += __shfl_xor(a7, 32);
        if (sub == 0) {
            *(float4*)&xs[m][8 * off]     = make_float4(a0, a1, a2, a3);
            *(float4*)&xs[m][8 * off + 4] = make_float4(a4, a5, a6, a7);
        }
    }
    __syncthreads();

    // ---- GEMM phase ----
    constexpr int G = 256 / J;
    constexpr int NM = M / G;
    const int gq = tid / J;
    const int j = tid % J;
    const int mbase = gq * NM;
    float acc[NM];
#pragma unroll
    for (int m = 0; m < NM; ++m) acc[m] = 0.f;

    for (int k = 0; k < D_H; k += 4) {
        float w0 = W[(k + 0) * J + j];
        float w1 = W[(k + 1) * J + j];
        float w2 = W[(k + 2) * J + j];
        float w3 = W[(k + 3) * J + j];
#pragma unroll
        for (int m = 0; m < NM; ++m) {
            float4 xv = *(const float4*)&xs[mbase + m][k];   // wave-uniform broadcast
            acc[m] += xv.x * w0 + xv.y * w1 + xv.z * w2 + xv.w * w3;
        }
    }
#pragma unroll
    for (int m = 0; m < NM; ++m) {
        int n = base + mbase + m;
        if (LAST) __builtin_nontemporal_store(acc[m], &outf[(size_t)n * J + j]);
        else      __builtin_nontemporal_store(f2bf(acc[m]), &outb[(size_t)n * J + j]);
    }
    // write sentinel zero row NN of the NEXT table (once per grid)
    if (!LAST && blockIdx.x == 0 && tid < 32) {
        ((uint2*)(outb + (size_t)NN * D_H))[tid] = make_uint2(0u, 0u);
    }
}

extern "C" void kernel_launch(void* const* d_in, const int* in_sizes, int n_in,
                              void* d_out, int out_size, void* d_ws, size_t ws_size,
                              hipStream_t stream) {
    const float* features = (const float*)d_in[0];
    const float* W0       = (const float*)d_in[1];
    const float* W1       = (const float*)d_in[2];
    const float* W2       = (const float*)d_in[3];
    const int*   src      = (const int*)d_in[4];
    const int*   dst      = (const int*)d_in[5];
    float* out = (float*)d_out;

    // Workspace: coarse_cnt | cnt | colbuf(ushort) | coarse | hb0 | hb1 | hb2 (~14 MB)
    int* coarse_cnt        = (int*)d_ws;                          // 160 ints
    int* cnt               = coarse_cnt + 160;                    // NN
    unsigned short* colbuf = (unsigned short*)(cnt + NN);         // NN*CAP ushorts
    unsigned* coarse       = (unsigned*)(colbuf + (size_t)NN * CAP);  // GRP*CAPC
    unsigned* hb0          = coarse + (size_t)GRP * CAPC;         // (NN+1)*64 uints
    unsigned* hb1          = hb0 + (size_t)(NN + 1) * 64;
    unsigned* hb2          = hb1 + (size_t)(NN + 1) * 64;

    hipMemsetAsync(coarse_cnt, 0, GRP * sizeof(int), stream);
    prep_a<<<AB + CB, 256, 0, stream>>>(src, dst, coarse_cnt, coarse, features, hb0);
    prep_b<<<GRP, 256, 0, stream>>>(coarse_cnt, coarse, cnt, colbuf);

    constexpr int M = 8;           // 10000/8 = 1250 blocks -> ~4.9 waves/SIMD
    gin_layer<D_H, M, false><<<NN / M, 256, 0, stream>>>((const uint4*)hb0, cnt, colbuf, W0,
                                                         (unsigned short*)hb1, nullptr);
    gin_layer<D_H, M, false><<<NN / M, 256, 0, stream>>>((const uint4*)hb1, cnt, colbuf, W1,
                                                         (unsigned short*)hb2, nullptr);
    gin_layer<N_CLS, M, true><<<NN / M, 256, 0, stream>>>((const uint4*)hb2, cnt, colbuf, W2,
                                                          nullptr, out);
}

// Round 8
// 147.611 us; speedup vs baseline: 1.2130x; 1.0118x over previous
//
#include <hip/hip_runtime.h>
#include <hip/hip_bf16.h>

#define NN 10000
#define NE 640000
#define D_IN 128
#define D_H 128
#define N_CLS 64
#define CAP 160    // per-node capacity (ushort entries): mean 64 sigma 8 -> +12 sigma
#define GRP 157    // coarse groups: dst>>6 (64 nodes/group)
#define CAPC 4800  // per-group coarse capacity: mean 4096 sigma 64 -> +11 sigma
#define EPB 1024   // edges per phase-A block
#define AB 625     // phase-A edge blocks (625*1024 == 640000)
#define CB 1251    // conv blocks: (NN+1)*32 uint2 / 256 rounded up (includes zero row NN)
#define CCS 16     // coarse_cnt stride (ints) -> one counter per 64B line

// ---- bf16 helpers ----
__device__ __forceinline__ float blo(unsigned u) { return __uint_as_float(u << 16); }
__device__ __forceinline__ float bhi(unsigned u) { return __uint_as_float(u & 0xffff0000u); }
__device__ __forceinline__ unsigned short f2bf(float f) {
    unsigned u = __float_as_uint(f);
    return (unsigned short)((u + 0x7fffu + ((u >> 16) & 1u)) >> 16);
}

// ---- Phase A: coarse-bucket edges (dst>>6) + fused f32->bf16 feature conv ----
__global__ __launch_bounds__(256) void prep_a(const int* __restrict__ src,
                                              const int* __restrict__ dst,
                                              int* __restrict__ coarse_cnt,
                                              unsigned* __restrict__ coarse,
                                              const float* __restrict__ feat,
                                              unsigned* __restrict__ hb0) {
    int bid = blockIdx.x;
    if (bid >= AB) {   // ---- conv part: fill (NN+1) x 128 bf16 table (row NN = zeros) ----
        int t = (bid - AB) * 256 + threadIdx.x;   // uint2 units, 4 elems each
        if (t < NN * 32) {
            float4 f = ((const float4*)feat)[t];
            unsigned lo = (unsigned)f2bf(f.x) | ((unsigned)f2bf(f.y) << 16);
            unsigned hi = (unsigned)f2bf(f.z) | ((unsigned)f2bf(f.w) << 16);
            ((uint2*)hb0)[t] = make_uint2(lo, hi);
        } else if (t < (NN + 1) * 32) {
            ((uint2*)hb0)[t] = make_uint2(0u, 0u);   // sentinel zero row
        }
        return;
    }
    __shared__ unsigned stage[EPB];
    __shared__ int hist[GRP], gbase[GRP], cur[GRP];
    const int t = threadIdx.x;
    for (int i = t; i < GRP; i += 256) hist[i] = 0;
    __syncthreads();
    const int e0 = bid * EPB;
    for (int i = t; i < EPB; i += 256) {
        int s = src[e0 + i];
        int d = dst[e0 + i];
        stage[i] = (unsigned)s | ((unsigned)d << 16);
        atomicAdd(&hist[d >> 6], 1);
    }
    __syncthreads();
    for (int i = t; i < GRP; i += 256) {
        gbase[i] = atomicAdd(&coarse_cnt[i * CCS], hist[i]);
        cur[i] = 0;
    }
    __syncthreads();
    for (int i = t; i < EPB; i += 256) {
        unsigned u = stage[i];
        int g = u >> 22;                 // dst >> 6
        int r = atomicAdd(&cur[g], 1);
        coarse[g * CAPC + gbase[g] + r] = u;
    }
}

// ---- Phase B: per-group scatter into per-node ushort colbuf + pad to x4 ----
__global__ __launch_bounds__(1024) void prep_b(const int* __restrict__ coarse_cnt,
                                               const unsigned* __restrict__ coarse,
                                               int* __restrict__ cnt,
                                               unsigned short* __restrict__ colbuf) {
    __shared__ int cur[64];
    const int g = blockIdx.x;
    const int t = threadIdx.x;
    if (t < 64) cur[t] = 0;
    __syncthreads();
    const int m = coarse_cnt[g * CCS];
    const unsigned* cb = coarse + g * CAPC;
    for (int i = t; i < m; i += 1024) {
        unsigned u = cb[i];
        int s = (int)(u & 0xFFFFu);
        int d = (int)(u >> 16);
        int r = atomicAdd(&cur[d - (g << 6)], 1);
        colbuf[d * CAP + r] = (unsigned short)s;
    }
    __syncthreads();
    if (t < 64) {
        int n = (g << 6) + t;
        if (n < NN) {
            int c = cur[t];
            int pad = (4 - (c & 3)) & 3;             // pad with sentinel NN (zero row)
            unsigned short* base = colbuf + n * CAP;
            for (int k = 0; k < pad; ++k) base[c + k] = (unsigned short)NN;
            cnt[n] = c + pad;
        }
    }
}

// ---- fused layer: M nodes/block; shfl-free tail-free gather + (h+agg)@W ----
template <int J, int M, bool LAST>
__global__ __launch_bounds__(256) void gin_layer(const uint4* __restrict__ hb4,   // (NN+1) x 16 uint4
                                                 const int* __restrict__ cnt,
                                                 const unsigned short* __restrict__ colbuf,
                                                 const float* __restrict__ W,     // 128 x J
                                                 unsigned short* __restrict__ outb,
                                                 float* __restrict__ outf) {
    __shared__ float xs[M][D_H];
    const int base = blockIdx.x * M;
    const int tid = threadIdx.x;
    const int wave = tid >> 6;
    const int lane = tid & 63;
    const int sub = lane >> 4;    // which of 4 rows in an index-group
    const int off = lane & 15;    // uint4 offset within a row

#pragma unroll 1
    for (int nm = 0; nm < M / 4; ++nm) {
        const int m = wave + nm * 4;
        const int n = base + m;
        float a0, a1, a2, a3, a4, a5, a6, a7;
        if (sub == 0) {           // own row (eps=0: h + agg), counted once
            uint4 u = hb4[n * 16 + off];
            a0 = blo(u.x); a1 = bhi(u.x); a2 = blo(u.y); a3 = bhi(u.y);
            a4 = blo(u.z); a5 = bhi(u.z); a6 = blo(u.w); a7 = bhi(u.w);
        } else {
            a0 = a1 = a2 = a3 = a4 = a5 = a6 = a7 = 0.f;
        }
        const int G4 = cnt[n] >> 2;                 // index-groups of 4 rows
        const uint2* cl8 = (const uint2*)(colbuf + n * CAP);
        int g = 0;
        for (; g + 4 <= G4; g += 4) {               // 16 rows in flight
            uint2 p0 = cl8[g + 0];
            uint2 p1 = cl8[g + 1];
            uint2 p2 = cl8[g + 2];
            uint2 p3 = cl8[g + 3];
            unsigned w0 = (sub & 2) ? p0.y : p0.x;
            unsigned w1 = (sub & 2) ? p1.y : p1.x;
            unsigned w2 = (sub & 2) ? p2.y : p2.x;
            unsigned w3 = (sub & 2) ? p3.y : p3.x;
            int s0 = (sub & 1) ? (w0 >> 16) : (w0 & 0xffffu);
            int s1 = (sub & 1) ? (w1 >> 16) : (w1 & 0xffffu);
            int s2 = (sub & 1) ? (w2 >> 16) : (w2 & 0xffffu);
            int s3 = (sub & 1) ? (w3 >> 16) : (w3 & 0xffffu);
            uint4 uA = hb4[s0 * 16 + off];
            uint4 uB = hb4[s1 * 16 + off];
            uint4 uC = hb4[s2 * 16 + off];
            uint4 uD = hb4[s3 * 16 + off];
            a0 += (blo(uA.x) + blo(uB.x)) + (blo(uC.x) + blo(uD.x));
            a1 += (bhi(uA.x) + bhi(uB.x)) + (bhi(uC.x) + bhi(uD.x));
            a2 += (blo(uA.y) + blo(uB.y)) + (blo(uC.y) + blo(uD.y));
            a3 += (bhi(uA.y) + bhi(uB.y)) + (bhi(uC.y) + bhi(uD.y));
            a4 += (blo(uA.z) + blo(uB.z)) + (blo(uC.z) + blo(uD.z));
            a5 += (bhi(uA.z) + bhi(uB.z)) + (bhi(uC.z) + bhi(uD.z));
            a6 += (blo(uA.w) + blo(uB.w)) + (blo(uC.w) + blo(uD.w));
            a7 += (bhi(uA.w) + bhi(uB.w)) + (bhi(uC.w) + bhi(uD.w));
        }
        for (; g < G4; ++g) {                       // <=3 remainder groups
            uint2 p = cl8[g];
            unsigned w = (sub & 2) ? p.y : p.x;
            int s = (sub & 1) ? (w >> 16) : (w & 0xffffu);
            uint4 u = hb4[s * 16 + off];
            a0 += blo(u.x); a1 += bhi(u.x); a2 += blo(u.y); a3 += bhi(u.y);
            a4 += blo(u.z); a5 += bhi(u.z); a6 += blo(u.w); a7 += bhi(u.w);
        }
        // reduce the 4 sub-rows
        a0 += __shfl_xor(a0, 16); a0 += __shfl_xor(a0, 32);
        a1 += __shfl_xor(a1, 16); a1 += __shfl_xor(a1, 32);
        a2 += __shfl_xor(a2, 16); a2 += __shfl_xor(a2, 32);
        a3 += __shfl_xor(a3, 16); a3 += __shfl_xor(a3, 32);
        a4 += __shfl_xor(a4, 16); a4 += __shfl_xor(a4, 32);
        a5 += __shfl_xor(a5, 16); a5 += __shfl_xor(a5, 32);
        a6 += __shfl_xor(a6, 16); a6 += __shfl_xor(a6, 32);
        a7 += __shfl_xor(a7, 16); a7 += __shfl_xor(a7, 32);
        if (sub == 0) {
            *(float4*)&xs[m][8 * off]     = make_float4(a0, a1, a2, a3);
            *(float4*)&xs[m][8 * off + 4] = make_float4(a4, a5, a6, a7);
        }
    }
    __syncthreads();

    // ---- GEMM phase ----
    constexpr int G = 256 / J;
    constexpr int NM = M / G;
    const int gq = tid / J;
    const int j = tid % J;
    const int mbase = gq * NM;
    float acc[NM];
#pragma unroll
    for (int m = 0; m < NM; ++m) acc[m] = 0.f;

    for (int k = 0; k < D_H; k += 4) {
        float w0 = W[(k + 0) * J + j];
        float w1 = W[(k + 1) * J + j];
        float w2 = W[(k + 2) * J + j];
        float w3 = W[(k + 3) * J + j];
#pragma unroll
        for (int m = 0; m < NM; ++m) {
            float4 xv = *(const float4*)&xs[mbase + m][k];   // wave-uniform broadcast
            acc[m] += xv.x * w0 + xv.y * w1 + xv.z * w2 + xv.w * w3;
        }
    }
#pragma unroll
    for (int m = 0; m < NM; ++m) {
        int n = base + mbase + m;
        if (LAST) __builtin_nontemporal_store(acc[m], &outf[(size_t)n * J + j]);
        else      __builtin_nontemporal_store(f2bf(acc[m]), &outb[(size_t)n * J + j]);
    }
    // write sentinel zero row NN of the NEXT table (once per grid)
    if (!LAST && blockIdx.x == 0 && tid < 32) {
        ((uint2*)(outb + (size_t)NN * D_H))[tid] = make_uint2(0u, 0u);
    }
}

extern "C" void kernel_launch(void* const* d_in, const int* in_sizes, int n_in,
                              void* d_out, int out_size, void* d_ws, size_t ws_size,
                              hipStream_t stream) {
    const float* features = (const float*)d_in[0];
    const float* W0       = (const float*)d_in[1];
    const float* W1       = (const float*)d_in[2];
    const float* W2       = (const float*)d_in[3];
    const int*   src      = (const int*)d_in[4];
    const int*   dst      = (const int*)d_in[5];
    float* out = (float*)d_out;

    // Workspace: coarse_cnt | cnt | colbuf(ushort) | coarse | hb0 | hb1 | hb2 (~14 MB)
    int* coarse_cnt        = (int*)d_ws;                          // GRP*CCS ints (line-padded)
    int* cnt               = coarse_cnt + GRP * CCS;              // NN
    unsigned short* colbuf = (unsigned short*)(cnt + NN);         // NN*CAP ushorts
    unsigned* coarse       = (unsigned*)(colbuf + (size_t)NN * CAP);  // GRP*CAPC
    unsigned* hb0          = coarse + (size_t)GRP * CAPC;         // (NN+1)*64 uints
    unsigned* hb1          = hb0 + (size_t)(NN + 1) * 64;
    unsigned* hb2          = hb1 + (size_t)(NN + 1) * 64;

    hipMemsetAsync(coarse_cnt, 0, GRP * CCS * sizeof(int), stream);
    prep_a<<<AB + CB, 256, 0, stream>>>(src, dst, coarse_cnt, coarse, features, hb0);
    prep_b<<<GRP, 1024, 0, stream>>>(coarse_cnt, coarse, cnt, colbuf);

    constexpr int M = 8;           // 10000/8 = 1250 blocks -> ~4.9 waves/SIMD
    gin_layer<D_H, M, false><<<NN / M, 256, 0, stream>>>((const uint4*)hb0, cnt, colbuf, W0,
                                                         (unsigned short*)hb1, nullptr);
    gin_layer<D_H, M, false><<<NN / M, 256, 0, stream>>>((const uint4*)hb1, cnt, colbuf, W1,
                                                         (unsigned short*)hb2, nullptr);
    gin_layer<N_CLS, M, true><<<NN / M, 256, 0, stream>>>((const uint4*)hb2, cnt, colbuf, W2,
                                                          nullptr, out);
}